// Round 14
// baseline (145.977 us; speedup 1.0000x reference)
//
#include <hip/hip_runtime.h>
#include <math.h>
#include <stdint.h>

#define ALPHA 0.2f

typedef __attribute__((ext_vector_type(8)))  short bf16x8;
typedef __attribute__((ext_vector_type(4)))  float f32x4;
typedef __attribute__((ext_vector_type(16))) float f32x16;

__device__ __forceinline__ uint32_t pack_bf16(float a, float b) {
    return ((__float_as_uint(a) + 0x8000u) >> 16) |
           ((__float_as_uint(b) + 0x8000u) & 0xFFFF0000u);
}
__device__ __forceinline__ unsigned short bf16_1(float a) {
    return (unsigned short)((__float_as_uint(a) + 0x8000u) >> 16);
}

// ---------------------------------------------------------------------------
// Kernel 1: k_pre — ROUND-23: MFMA GEMM (r13, passed, absmax 0.113) with the
// 320-shfl Wh1/Wh2 reduction replaced by ALGEBRA:
//   Wh1 = (x^T W) a1 = x^T (W a1).  Wa1/Wa2 (64-vec) accumulated during W
//   staging via LDS atomicAdd (each staging thread holds W[f][o0..3]), bf16-
//   converted once, appended as cols 0/1 of a 5th B-tile -> 4 extra MFMA
//   produce acc5: lane col0 = Wh1 rows, col1 = Wh2 rows. Direct stores, zero
//   shuffles (was 16 regs x 5 steps x 2 = 320 serial shfl+add per thread —
//   the dominant non-staging cost; k_pre ~46us vs ~10us floor).
//   Precision: one extra bf16 rounding (Wa) on an already-bf16 path.
//   DECLARED RISK: absmax 0.113 -> expect <=0.15 (threshold 0.18375);
//   revert plan = restore shfl path.
//   Everything else identical to r13 (verified): blocks 0..511 wh
//   (b=blk&7, jt32=(blk>>3)&31, th=blk>>8), xbf/Wbf bf16 LDS XOR-swizzled,
//   16 MFMA main GEMM, D->Whf B-frag in-register conversion.
//   Blocks 512..1023: adjb (unchanged).
//   RULE #20: all acc/pk indices compile-time.
// ---------------------------------------------------------------------------
__global__ __launch_bounds__(256) void k_pre(const float* __restrict__ x,
                                             const float* __restrict__ W,
                                             const float* __restrict__ a,
                                             const float* __restrict__ adj,
                                             uint4* __restrict__ Whf,
                                             float* __restrict__ Wh1,
                                             float* __restrict__ Wh2,
                                             unsigned char* __restrict__ adjq) {
    __shared__ __attribute__((aligned(16))) unsigned short xbf[4 * 32 * 64]; // 16 KB
    __shared__ __attribute__((aligned(16))) unsigned short Wbf[128 * 64];    // 16 KB
    __shared__ float Wa1s[64], Wa2s[64];                                     // 512 B
    __shared__ __attribute__((aligned(16))) unsigned short Wab1[64], Wab2[64]; // 256 B

    if (blockIdx.x >= 512) {
        // ---- adjb part: 512 blocks x 256 threads, idx 0..131071 ----
        int idx = (blockIdx.x - 512) * 256 + threadIdx.x;
        int i   = idx >> 7;
        int pos = idx & 127;                            // jg
        const float4* a4 = (const float4*)adj + idx * 2;
        float4 v0 = a4[0], v1 = a4[1];
        unsigned int by = 0;
        by |= (v0.x > 0.f) ? 1u : 0u;
        by |= (v0.y > 0.f) ? 2u : 0u;
        by |= (v0.z > 0.f) ? 4u : 0u;
        by |= (v0.w > 0.f) ? 8u : 0u;
        by |= (v1.x > 0.f) ? 16u : 0u;
        by |= (v1.y > 0.f) ? 32u : 0u;
        by |= (v1.z > 0.f) ? 64u : 0u;
        by |= (v1.w > 0.f) ? 128u : 0u;
        adjq[(i << 7) + ((pos & 1) << 6) + (((pos >> 1) & 1) << 5) + (pos >> 2)] =
            (unsigned char)by;
        return;
    }

    const int tid  = threadIdx.x;
    const int b    = blockIdx.x & 7;
    const int jt32 = (blockIdx.x >> 3) & 31;      // 32-row j-tile
    const int th   = blockIdx.x >> 8;             // t-half 0/1

    // zero Wa accumulators before staging atomics
    if (tid < 64) { Wa1s[tid] = 0.f; Wa2s[tid] = 0.f; }
    __syncthreads();

    // ---- stage x: 32j x 64f x 4t fp32 -> bf16 LDS [t_loc][j][f], swizzled
    const float* xg = x + ((size_t)(b * 1024 + jt32 * 32) * 64) * 8 + th * 4;
    #pragma unroll
    for (int i = 0; i < 8; ++i) {
        int idx = tid + i * 256;                  // 0..2047
        int j   = idx >> 6;
        int f   = idx & 63;
        float4 v = *(const float4*)(xg + (size_t)(j * 64 + f) * 8);
        const int sw = ((j & 7) << 4);
        *(unsigned short*)((char*)xbf + ((((0 * 32 + j) * 64 + f) * 2) ^ sw)) = bf16_1(v.x);
        *(unsigned short*)((char*)xbf + ((((1 * 32 + j) * 64 + f) * 2) ^ sw)) = bf16_1(v.y);
        *(unsigned short*)((char*)xbf + ((((2 * 32 + j) * 64 + f) * 2) ^ sw)) = bf16_1(v.z);
        *(unsigned short*)((char*)xbf + ((((3 * 32 + j) * 64 + f) * 2) ^ sw)) = bf16_1(v.w);
    }
    // ---- stage W: 64f x 128o fp32 -> bf16 LDS [o][f] transposed, swizzled;
    //      simultaneously accumulate Wa1/Wa2 = W·a1 / W·a2 via LDS atomics
    const float4* Wg4 = (const float4*)W;
    const float4* a14 = (const float4*)a;         // a[0..127]
    const float4* a24 = (const float4*)(a + 128); // a[128..255]
    #pragma unroll
    for (int i = 0; i < 8; ++i) {
        int idx = tid + i * 256;                  // 0..2047
        int fr  = idx >> 5;
        int oq  = idx & 31;                       // o-quad
        int o0  = oq * 4;
        float4 v  = Wg4[idx];
        float4 c1 = a14[oq];
        float4 c2 = a24[oq];
        #pragma unroll
        for (int c = 0; c < 4; ++c) {
            int o = o0 + c;
            *(unsigned short*)((char*)Wbf + (((o * 64 + fr) * 2) ^ ((o & 7) << 4))) =
                bf16_1((&v.x)[c]);
        }
        float p1 = v.x * c1.x + v.y * c1.y + v.z * c1.z + v.w * c1.w;
        float p2 = v.x * c2.x + v.y * c2.y + v.z * c2.z + v.w * c2.w;
        atomicAdd(&Wa1s[fr], p1);
        atomicAdd(&Wa2s[fr], p2);
    }
    __syncthreads();
    if (tid < 64) {
        Wab1[tid] = bf16_1(Wa1s[tid]);
        Wab2[tid] = bf16_1(Wa2s[tid]);
    }
    __syncthreads();

    const int w   = tid >> 6;                     // wave 0..3
    const int l   = tid & 63;
    const int col = l & 31;
    const int g   = l >> 5;
    const int t   = th * 4 + w;
    const int bt  = b * 8 + t;

    f32x16 acc[4];
    #pragma unroll
    for (int nt2 = 0; nt2 < 4; ++nt2)
        #pragma unroll
        for (int r = 0; r < 16; ++r) acc[nt2][r] = 0.f;
    f32x16 acc5;
    #pragma unroll
    for (int r = 0; r < 16; ++r) acc5[r] = 0.f;

    // ---- 20 MFMA: 4 o-tiles + Wa-tile, K=64 in 4 steps of 16
    #pragma unroll
    for (int kk = 0; kk < 4; ++kk) {
        union { uint4 u4; bf16x8 v8; } av;
        const int abyte = (((w * 32 + col) * 64 + kk * 16 + g * 8) * 2) ^ ((col & 7) << 4);
        av.u4 = *(const uint4*)((const char*)xbf + abyte);
        #pragma unroll
        for (int nt2 = 0; nt2 < 4; ++nt2) {
            union { uint4 u4; bf16x8 v8; } bv;
            const int o     = nt2 * 32 + col;
            const int bbyte = ((o * 64 + kk * 16 + g * 8) * 2) ^ ((o & 7) << 4);
            bv.u4 = *(const uint4*)((const char*)Wbf + bbyte);
            acc[nt2] = __builtin_amdgcn_mfma_f32_32x32x16_bf16(
                av.v8, bv.v8, acc[nt2], 0, 0, 0);
        }
        // Wa tile: col0 = Wa1, col1 = Wa2, cols 2..31 = 0
        {
            const int ko = kk * 16 + g * 8;
            union { uint4 u4; bf16x8 v8; } bv5;
            const uint4 w1 = *(const uint4*)&Wab1[ko];
            const uint4 w2 = *(const uint4*)&Wab2[ko];
            uint4 z; z.x = z.y = z.z = z.w = 0u;
            bv5.u4 = (col == 0) ? w1 : (col == 1) ? w2 : z;
            acc5 = __builtin_amdgcn_mfma_f32_32x32x16_bf16(
                av.v8, bv5.v8, acc5, 0, 0, 0);
        }
    }

    // ---- Wh1/Wh2 direct from acc5 (no shuffles)
    if (col < 2) {
        float* dst = (col == 0) ? Wh1 : Wh2;
        #pragma unroll
        for (int reg = 0; reg < 16; ++reg) {
            int j = jt32 * 32 + (reg & 3) + 8 * (reg >> 2) + 4 * g;
            dst[bt * 1024 + j] = acc5[reg];
        }
    }

    // ---- D -> Whf B-frag conversion + store (verified r13)
    #pragma unroll
    for (int nt2 = 0; nt2 < 4; ++nt2) {
        const uint32_t pk0 = pack_bf16(acc[nt2][0],  acc[nt2][1]);
        const uint32_t pk1 = pack_bf16(acc[nt2][2],  acc[nt2][3]);
        const uint32_t pk2 = pack_bf16(acc[nt2][4],  acc[nt2][5]);
        const uint32_t pk3 = pack_bf16(acc[nt2][6],  acc[nt2][7]);
        const uint32_t pk4 = pack_bf16(acc[nt2][8],  acc[nt2][9]);
        const uint32_t pk5 = pack_bf16(acc[nt2][10], acc[nt2][11]);
        const uint32_t pk6 = pack_bf16(acc[nt2][12], acc[nt2][13]);
        const uint32_t pk7 = pack_bf16(acc[nt2][14], acc[nt2][15]);
        const uint32_t xp0 = __shfl_xor(pk0, 32);
        const uint32_t xp1 = __shfl_xor(pk1, 32);
        const uint32_t xp2 = __shfl_xor(pk2, 32);
        const uint32_t xp3 = __shfl_xor(pk3, 32);
        const uint32_t xp4 = __shfl_xor(pk4, 32);
        const uint32_t xp5 = __shfl_xor(pk5, 32);
        const uint32_t xp6 = __shfl_xor(pk6, 32);
        const uint32_t xp7 = __shfl_xor(pk7, 32);
        const bool gh = (g != 0);

        uint4 s0, s1q;
        s0.x  = gh ? xp2 : pk0;   // jsub0: e0,e1
        s0.y  = gh ? xp3 : pk1;   //        e2,e3
        s0.z  = gh ? pk2 : xp0;   //        e4,e5
        s0.w  = gh ? pk3 : xp1;   //        e6,e7
        s1q.x = gh ? xp6 : pk4;   // jsub1
        s1q.y = gh ? xp7 : pk5;
        s1q.z = gh ? pk6 : xp4;
        s1q.w = gh ? pk7 : xp5;

        const size_t base = ((size_t)(bt * 4 + nt2) * 64 + jt32 * 2) * 64 + l;
        Whf[base]      = s0;      // jt16 = jt32*2
        Whf[base + 64] = s1q;     // jt16 = jt32*2 + 1
    }
}

// ---------------------------------------------------------------------------
// Kernel 2: k_agg — EXACT round-7 version (52.x us verified across r6/r7/r13;
// 76 VGPR, zero scratch, LDS 41 KB). k_agg restructuring CLOSED (r8/r11/r12
// + r10/r12/r13/r14 spills): ~170-reg live set pins 3 waves/SIMD.
// Layouts: A idx=lane&31, k=(lane>>5)*8+e; D col=lane&31,
// row=(reg&3)+8*(reg>>2)+4*(lane>>5); l_i via ones-MFMA.
// Grid 512: blockIdx = ((itile*8 + t)*8 + b) -> XCD = b.
// ---------------------------------------------------------------------------
__global__ __launch_bounds__(256) void k_agg(const uint4* __restrict__ Whf,
                                             const float* __restrict__ Wh1,
                                             const float* __restrict__ Wh2,
                                             const unsigned char* __restrict__ adjq,
                                             float* __restrict__ out) {
    __shared__ __attribute__((aligned(16))) uint4 bstage[2][1024];  // 32 KB
    __shared__ __attribute__((aligned(16))) float efsE[1024];       // 4 KB
    __shared__ __attribute__((aligned(16))) float efsF[1024];       // 4 KB
    __shared__ float m2s[4];

    const int tid   = threadIdx.x;
    const int b     = blockIdx.x & 7;
    const int t     = (blockIdx.x >> 3) & 7;
    const int itile = blockIdx.x >> 6;            // 0..7
    const int bt    = b * 8 + t;
    const int i0    = itile * 128;

    const int w   = tid >> 6;                     // wave 0..3 (= ntile chunk)
    const int l   = tid & 63;
    const int col = l & 31;
    const int g   = l >> 5;                       // k-half group
    const int row = w * 32 + col;                 // block-local i-row

    const uint4* plane = Whf + (size_t)bt * 16384;

    // prefetch superstep 0 (kf 0..3 of this wave's ntile chunk)
    uint4 pf[4];
    #pragma unroll
    for (int f = 0; f < 4; ++f) pf[f] = plane[(w * 64 + f) * 64 + l];

    // adj mask regs: 64 B at (i0+row)*128 + g*64
    const uint4* ap = (const uint4*)(adjq + ((size_t)(i0 + row) << 7) + (g << 6));
    uint4 am[4];
    #pragma unroll
    for (int f = 0; f < 4; ++f) am[f] = ap[f];

    // stage E/F (separate fp32) + running max of h2; h1 direct per-thread
    const float* wh2g = Wh2 + bt * 1024;
    float mx = -1e30f;
    #pragma unroll
    for (int rep = 0; rep < 4; ++rep) {
        int   j  = tid + rep * 256;
        float h2 = wh2g[j];
        efsE[j] = __expf(h2);
        efsF[j] = __expf(ALPHA * h2);
        mx = fmaxf(mx, h2);
    }
    #pragma unroll
    for (int off = 1; off < 64; off <<= 1) mx = fmaxf(mx, __shfl_xor(mx, off));
    if (l == 0) m2s[w] = mx;
    const float h1 = Wh1[bt * 1024 + i0 + row];

    #pragma unroll
    for (int f = 0; f < 4; ++f) bstage[0][(w * 4 + f) * 64 + l] = pf[f];
    __syncthreads();

    const float M2 = fmaxf(fmaxf(m2s[0], m2s[1]), fmaxf(m2s[2], m2s[3]));
    const float e0 = h1 + M2;
    const float mp = fmaxf(e0, ALPHA * e0);       // both products <= 1
    const float Af = __expf(h1 - mp);
    const float Bf = __expf(ALPHA * h1 - mp);

    f32x16 acc[4];
    #pragma unroll
    for (int nt2 = 0; nt2 < 4; ++nt2)
        #pragma unroll
        for (int r = 0; r < 16; ++r) acc[nt2][r] = 0.f;
    f32x16 accl;
    #pragma unroll
    for (int r = 0; r < 16; ++r) accl[r] = 0.f;

    bf16x8 ones;
    #pragma unroll
    for (int i = 0; i < 8; ++i) ones[i] = (short)0x3F80;

    #pragma unroll
    for (int v = 0; v < 16; ++v) {
        if (v + 1 < 16) {
            #pragma unroll
            for (int f = 0; f < 4; ++f)
                pf[f] = plane[(w * 64 + (v + 1) * 4 + f) * 64 + l];
        }

        #pragma unroll
        for (int ts = 0; ts < 4; ++ts) {          // 16-j MFMA slice
            const int jb = v * 64 + ts * 16 + g * 8;
            float4 E0 = *(const float4*)&efsE[jb];
            float4 E1 = *(const float4*)&efsE[jb + 4];
            float4 F0 = *(const float4*)&efsF[jb];
            float4 F1 = *(const float4*)&efsF[jb + 4];

            // adj byte (static select after full unroll)
            const int      pe = (ts & 1) * 32 + (v >> 1) * 4 + (v & 1) * 2 + (ts >> 1);
            const uint4    av = am[pe >> 4];
            const int      cc = (pe >> 2) & 3;
            const uint32_t cw = (cc == 0) ? av.x : (cc == 1) ? av.y
                               : (cc == 2) ? av.z : av.w;
            const uint32_t by = (cw >> ((pe & 3) * 8)) & 0xFFu;

            float p[8];
            p[0] = fmaxf(Af * E0.x, Bf * F0.x) * (float)((by >> 0) & 1u);
            p[1] = fmaxf(Af * E0.y, Bf * F0.y) * (float)((by >> 1) & 1u);
            p[2] = fmaxf(Af * E0.z, Bf * F0.z) * (float)((by >> 2) & 1u);
            p[3] = fmaxf(Af * E0.w, Bf * F0.w) * (float)((by >> 3) & 1u);
            p[4] = fmaxf(Af * E1.x, Bf * F1.x) * (float)((by >> 4) & 1u);
            p[5] = fmaxf(Af * E1.y, Bf * F1.y) * (float)((by >> 5) & 1u);
            p[6] = fmaxf(Af * E1.z, Bf * F1.z) * (float)((by >> 6) & 1u);
            p[7] = fmaxf(Af * E1.w, Bf * F1.w) * (float)((by >> 7) & 1u);

            union { uint32_t u32[4]; bf16x8 v8; } pk;
            #pragma unroll
            for (int r = 0; r < 4; ++r)
                pk.u32[r] = pack_bf16(p[2 * r], p[2 * r + 1]);

            #pragma unroll
            for (int nt2 = 0; nt2 < 4; ++nt2) {
                union { uint4 u4; bf16x8 v8; } br;
                br.u4 = bstage[v & 1][(nt2 * 4 + ts) * 64 + l];
                acc[nt2] = __builtin_amdgcn_mfma_f32_32x32x16_bf16(
                    pk.v8, br.v8, acc[nt2], 0, 0, 0);
            }
            accl = __builtin_amdgcn_mfma_f32_32x32x16_bf16(
                pk.v8, ones, accl, 0, 0, 0);
        }

        if (v + 1 < 16) {
            #pragma unroll
            for (int f = 0; f < 4; ++f)
                bstage[(v + 1) & 1][(w * 4 + f) * 64 + l] = pf[f];
        }
        __syncthreads();
    }

    // epilogue: D rows r = (reg&3)+8*(reg>>2)+4*g; accl rows identical
    float* og = out + ((size_t)(b * 1024 + i0 + w * 32)) * 1024 + t;
    #pragma unroll
    for (int reg = 0; reg < 16; ++reg) {
        const int   r    = (reg & 3) + 8 * (reg >> 2) + 4 * g;
        const float linv = 1.0f / accl[reg];
        #pragma unroll
        for (int nt2 = 0; nt2 < 4; ++nt2) {
            float vv = acc[nt2][reg] * linv;
            vv = vv > 0.f ? vv : __expf(vv) - 1.f;
            og[(size_t)r * 1024 + (nt2 * 32 + col) * 8] = vv;
        }
    }
}

// ---------------------------------------------------------------------------
extern "C" void kernel_launch(void* const* d_in, const int* in_sizes, int n_in,
                              void* d_out, int out_size, void* d_ws, size_t ws_size,
                              hipStream_t stream) {
    const float* x   = (const float*)d_in[0];   // (8,1024,64,8)
    const float* adj = (const float*)d_in[1];   // (1024,1024)
    const float* W   = (const float*)d_in[2];   // (64,128)
    const float* a   = (const float*)d_in[3];   // (256,1)
    float* out = (float*)d_out;                 // (8,1024,128,8)

    uint4*         Whf  = (uint4*)d_ws;                        // 1048576 uint4 = 16 MB
    float*         Wh1  = (float*)(Whf + 1048576);             // 65536 f
    float*         Wh2  = Wh1 + 65536;                         // 65536 f
    unsigned char* adjq = (unsigned char*)(Wh2 + 65536);       // 131072 B

    k_pre<<<1024, 256, 0, stream>>>(x, W, a, adj, Whf, Wh1, Wh2, adjq);
    k_agg<<<512, 256, 0, stream>>>(Whf, Wh1, Wh2, adjq, out);
}

// Round 15
// 135.173 us; speedup vs baseline: 1.0799x; 1.0799x over previous
//
#include <hip/hip_runtime.h>
#include <math.h>
#include <stdint.h>

#define ALPHA 0.2f

typedef __attribute__((ext_vector_type(8)))  short bf16x8;
typedef __attribute__((ext_vector_type(4)))  float f32x4;
typedef __attribute__((ext_vector_type(16))) float f32x16;

__device__ __forceinline__ uint32_t pack_bf16(float a, float b) {
    return ((__float_as_uint(a) + 0x8000u) >> 16) |
           ((__float_as_uint(b) + 0x8000u) & 0xFFFF0000u);
}
__device__ __forceinline__ unsigned short bf16_1(float a) {
    return (unsigned short)((__float_as_uint(a) + 0x8000u) >> 16);
}

// ---------------------------------------------------------------------------
// Kernel 1: k_pre — r13 version RESTORED (shfl Wh1/Wh2; r14's LDS-atomic Wa
// path cost +10.9us from 32-way atomic contention — reverted). One change:
// adjb writes the NEW adjq ordering consumed by the barrier-free k_agg:
//   byte (i, jg) with jg = v*8 + ts*2 + g  ->  addr i*128 + g*64 + v*4 + ts
//   = (i<<7) + ((jg&1)<<6) + ((jg>>3)<<2) + ((jg>>1)&3)
// so k_agg reads ONE u32 per superstep at arow + v*4 (no am[] reg array).
// Accounting (r13/r14 solve): fixed overhead ~75us, k_pre ~7us, k_agg 52.5.
// ---------------------------------------------------------------------------
__global__ __launch_bounds__(256) void k_pre(const float* __restrict__ x,
                                             const float* __restrict__ W,
                                             const float* __restrict__ a,
                                             const float* __restrict__ adj,
                                             uint4* __restrict__ Whf,
                                             float* __restrict__ Wh1,
                                             float* __restrict__ Wh2,
                                             unsigned char* __restrict__ adjq) {
    __shared__ __attribute__((aligned(16))) unsigned short xbf[4 * 32 * 64]; // 16 KB
    __shared__ __attribute__((aligned(16))) unsigned short Wbf[128 * 64];    // 16 KB

    if (blockIdx.x >= 512) {
        // ---- adjb part: 512 blocks x 256 threads, idx 0..131071 ----
        int idx = (blockIdx.x - 512) * 256 + threadIdx.x;
        int i   = idx >> 7;
        int pos = idx & 127;                            // jg
        const float4* a4 = (const float4*)adj + idx * 2;
        float4 v0 = a4[0], v1 = a4[1];
        unsigned int by = 0;
        by |= (v0.x > 0.f) ? 1u : 0u;
        by |= (v0.y > 0.f) ? 2u : 0u;
        by |= (v0.z > 0.f) ? 4u : 0u;
        by |= (v0.w > 0.f) ? 8u : 0u;
        by |= (v1.x > 0.f) ? 16u : 0u;
        by |= (v1.y > 0.f) ? 32u : 0u;
        by |= (v1.z > 0.f) ? 64u : 0u;
        by |= (v1.w > 0.f) ? 128u : 0u;
        // NEW ordering: i*128 + g*64 + v*4 + ts  (g=jg&1, v=jg>>3, ts=(jg>>1)&3)
        adjq[(i << 7) + ((pos & 1) << 6) + ((pos >> 3) << 2) + ((pos >> 1) & 3)] =
            (unsigned char)by;
        return;
    }

    const int tid  = threadIdx.x;
    const int b    = blockIdx.x & 7;
    const int jt32 = (blockIdx.x >> 3) & 31;      // 32-row j-tile
    const int th   = blockIdx.x >> 8;             // t-half 0/1

    // ---- stage x: 32j x 64f x 4t fp32 -> bf16 LDS [t_loc][j][f], swizzled
    const float* xg = x + ((size_t)(b * 1024 + jt32 * 32) * 64) * 8 + th * 4;
    #pragma unroll
    for (int i = 0; i < 8; ++i) {
        int idx = tid + i * 256;                  // 0..2047
        int j   = idx >> 6;
        int f   = idx & 63;
        float4 v = *(const float4*)(xg + (size_t)(j * 64 + f) * 8);
        const int sw = ((j & 7) << 4);
        *(unsigned short*)((char*)xbf + ((((0 * 32 + j) * 64 + f) * 2) ^ sw)) = bf16_1(v.x);
        *(unsigned short*)((char*)xbf + ((((1 * 32 + j) * 64 + f) * 2) ^ sw)) = bf16_1(v.y);
        *(unsigned short*)((char*)xbf + ((((2 * 32 + j) * 64 + f) * 2) ^ sw)) = bf16_1(v.z);
        *(unsigned short*)((char*)xbf + ((((3 * 32 + j) * 64 + f) * 2) ^ sw)) = bf16_1(v.w);
    }
    // ---- stage W: 64f x 128o fp32 -> bf16 LDS [o][f] (transposed), swizzled
    const float4* Wg4 = (const float4*)W;
    #pragma unroll
    for (int i = 0; i < 8; ++i) {
        int idx = tid + i * 256;                  // 0..2047
        int fr  = idx >> 5;
        int o0  = (idx & 31) * 4;
        float4 v = Wg4[idx];
        #pragma unroll
        for (int c = 0; c < 4; ++c) {
            int o = o0 + c;
            *(unsigned short*)((char*)Wbf + (((o * 64 + fr) * 2) ^ ((o & 7) << 4))) =
                bf16_1((&v.x)[c]);
        }
    }
    __syncthreads();

    const int w   = tid >> 6;                     // wave 0..3
    const int l   = tid & 63;
    const int col = l & 31;
    const int g   = l >> 5;
    const int t   = th * 4 + w;
    const int bt  = b * 8 + t;

    f32x16 acc[4];
    #pragma unroll
    for (int nt2 = 0; nt2 < 4; ++nt2)
        #pragma unroll
        for (int r = 0; r < 16; ++r) acc[nt2][r] = 0.f;

    // ---- 16 MFMA: D[32j x 32o] x4 o-tiles, K=64 in 4 steps of 16
    #pragma unroll
    for (int kk = 0; kk < 4; ++kk) {
        union { uint4 u4; bf16x8 v8; } av;
        const int abyte = (((w * 32 + col) * 64 + kk * 16 + g * 8) * 2) ^ ((col & 7) << 4);
        av.u4 = *(const uint4*)((const char*)xbf + abyte);
        #pragma unroll
        for (int nt2 = 0; nt2 < 4; ++nt2) {
            union { uint4 u4; bf16x8 v8; } bv;
            const int o     = nt2 * 32 + col;
            const int bbyte = ((o * 64 + kk * 16 + g * 8) * 2) ^ ((o & 7) << 4);
            bv.u4 = *(const uint4*)((const char*)Wbf + bbyte);
            acc[nt2] = __builtin_amdgcn_mfma_f32_32x32x16_bf16(
                av.v8, bv.v8, acc[nt2], 0, 0, 0);
        }
    }

    // ---- Wh1/Wh2: per-reg dot over o (in-thread over 4 tiles + 32-lane reduce)
    float a1v[4], a2v[4];
    #pragma unroll
    for (int nt2 = 0; nt2 < 4; ++nt2) {
        a1v[nt2] = a[nt2 * 32 + col];
        a2v[nt2] = a[128 + nt2 * 32 + col];
    }
    #pragma unroll
    for (int reg = 0; reg < 16; ++reg) {
        float s1 = acc[0][reg] * a1v[0] + acc[1][reg] * a1v[1]
                 + acc[2][reg] * a1v[2] + acc[3][reg] * a1v[3];
        float s2 = acc[0][reg] * a2v[0] + acc[1][reg] * a2v[1]
                 + acc[2][reg] * a2v[2] + acc[3][reg] * a2v[3];
        #pragma unroll
        for (int off = 1; off < 32; off <<= 1) {
            s1 += __shfl_xor(s1, off);
            s2 += __shfl_xor(s2, off);
        }
        if (col == 0) {
            int j = jt32 * 32 + (reg & 3) + 8 * (reg >> 2) + 4 * g;
            Wh1[bt * 1024 + j] = s1;
            Wh2[bt * 1024 + j] = s2;
        }
    }

    // ---- D -> Whf B-frag conversion + store (verified r13)
    #pragma unroll
    for (int nt2 = 0; nt2 < 4; ++nt2) {
        const uint32_t pk0 = pack_bf16(acc[nt2][0],  acc[nt2][1]);
        const uint32_t pk1 = pack_bf16(acc[nt2][2],  acc[nt2][3]);
        const uint32_t pk2 = pack_bf16(acc[nt2][4],  acc[nt2][5]);
        const uint32_t pk3 = pack_bf16(acc[nt2][6],  acc[nt2][7]);
        const uint32_t pk4 = pack_bf16(acc[nt2][8],  acc[nt2][9]);
        const uint32_t pk5 = pack_bf16(acc[nt2][10], acc[nt2][11]);
        const uint32_t pk6 = pack_bf16(acc[nt2][12], acc[nt2][13]);
        const uint32_t pk7 = pack_bf16(acc[nt2][14], acc[nt2][15]);
        const uint32_t xp0 = __shfl_xor(pk0, 32);
        const uint32_t xp1 = __shfl_xor(pk1, 32);
        const uint32_t xp2 = __shfl_xor(pk2, 32);
        const uint32_t xp3 = __shfl_xor(pk3, 32);
        const uint32_t xp4 = __shfl_xor(pk4, 32);
        const uint32_t xp5 = __shfl_xor(pk5, 32);
        const uint32_t xp6 = __shfl_xor(pk6, 32);
        const uint32_t xp7 = __shfl_xor(pk7, 32);
        const bool gh = (g != 0);

        uint4 s0, s1q;
        s0.x  = gh ? xp2 : pk0;   // jsub0: e0,e1
        s0.y  = gh ? xp3 : pk1;   //        e2,e3
        s0.z  = gh ? pk2 : xp0;   //        e4,e5
        s0.w  = gh ? pk3 : xp1;   //        e6,e7
        s1q.x = gh ? xp6 : pk4;   // jsub1
        s1q.y = gh ? xp7 : pk5;
        s1q.z = gh ? pk6 : xp4;
        s1q.w = gh ? pk7 : xp5;

        const size_t base = ((size_t)(bt * 4 + nt2) * 64 + jt32 * 2) * 64 + l;
        Whf[base]      = s0;      // jt16 = jt32*2
        Whf[base + 64] = s1q;     // jt16 = jt32*2 + 1
    }
}

// ---------------------------------------------------------------------------
// Kernel 2: k_agg — ROUND-24: BARRIER-FREE, controlled-liveness version.
//   Theory: r7's 52.5us has 45% combined pipe util; stall = 16 barrier
//   drains + LDS round-trip latency at 2-3 waves/SIMD. Previous de-barrier
//   attempts spilled via (1) full 64-step unroll hoisting loads (r5),
//   (2) launch-bounds caps (r10/r12), (3) runtime-indexed reg arrays (r10).
//   Each addressed here:
//   - #pragma unroll 1 on the v-loop: no cross-superstep hoisting.
//   - Two named q-banks (qX/qY) alternated by STATIC ts parity: WAR deps
//     bound in-flight B-frag loads to 32 regs.
//   - adjq RE-ORDERED (see k_pre) so the mask is ONE u32 load at arow+v*4
//     per superstep: am[] register array (16 regs + rule-#20 hazard) gone.
//   - Default launch bounds; E/F stay in LDS (broadcast reads, free);
//     ONE barrier total (prologue); setprio(1) around MFMA (T5 — waves are
//     now truly independent).
//   B-frags straight from global: frag(v,f,nt2) = plane[(nt2*64+v*4+f)*64+l];
//   4 waves/block read the same lines near-lockstep (L1 shares); per-XCD
//   working set 2MB (L2-fit).
//   KILL: VGPR>=200 or WRITE>>40MB -> spill invincible -> permanent r7.
// Layouts: A idx=lane&31, k=(lane>>5)*8+e; D col=lane&31,
// row=(reg&3)+8*(reg>>2)+4*(lane>>5); l_i via ones-MFMA.
// Grid 512: blockIdx = ((itile*8 + t)*8 + b) -> XCD = b.
// ---------------------------------------------------------------------------
#define TSBODY(TS, QU, QV, NEXTSLOT)                                          \
    {                                                                         \
        _Pragma("unroll")                                                     \
        for (int nt2 = 0; nt2 < 4; ++nt2)                                     \
            QV[nt2].u4 = plane[(nt2 * 64 + (NEXTSLOT)) * 64 + l];             \
        const int jb = v * 64 + (TS) * 16 + g * 8;                            \
        float4 E0 = *(const float4*)&efsE[jb];                                \
        float4 E1 = *(const float4*)&efsE[jb + 4];                            \
        float4 F0 = *(const float4*)&efsF[jb];                                \
        float4 F1 = *(const float4*)&efsF[jb + 4];                            \
        const uint32_t by = (by32 >> ((TS) * 8)) & 0xFFu;                     \
        float p[8];                                                           \
        p[0] = fmaxf(Af * E0.x, Bf * F0.x) * (float)((by >> 0) & 1u);         \
        p[1] = fmaxf(Af * E0.y, Bf * F0.y) * (float)((by >> 1) & 1u);         \
        p[2] = fmaxf(Af * E0.z, Bf * F0.z) * (float)((by >> 2) & 1u);         \
        p[3] = fmaxf(Af * E0.w, Bf * F0.w) * (float)((by >> 3) & 1u);         \
        p[4] = fmaxf(Af * E1.x, Bf * F1.x) * (float)((by >> 4) & 1u);         \
        p[5] = fmaxf(Af * E1.y, Bf * F1.y) * (float)((by >> 5) & 1u);         \
        p[6] = fmaxf(Af * E1.z, Bf * F1.z) * (float)((by >> 6) & 1u);         \
        p[7] = fmaxf(Af * E1.w, Bf * F1.w) * (float)((by >> 7) & 1u);         \
        union { uint32_t u32[4]; bf16x8 v8; } pk;                             \
        _Pragma("unroll")                                                     \
        for (int r = 0; r < 4; ++r)                                           \
            pk.u32[r] = pack_bf16(p[2 * r], p[2 * r + 1]);                    \
        __builtin_amdgcn_s_setprio(1);                                        \
        _Pragma("unroll")                                                     \
        for (int nt2 = 0; nt2 < 4; ++nt2)                                     \
            acc[nt2] = __builtin_amdgcn_mfma_f32_32x32x16_bf16(               \
                pk.v8, QU[nt2].v8, acc[nt2], 0, 0, 0);                        \
        accl = __builtin_amdgcn_mfma_f32_32x32x16_bf16(                       \
            pk.v8, ones, accl, 0, 0, 0);                                      \
        __builtin_amdgcn_s_setprio(0);                                        \
    }

__global__ __launch_bounds__(256) void k_agg(const uint4* __restrict__ Whf,
                                             const float* __restrict__ Wh1,
                                             const float* __restrict__ Wh2,
                                             const unsigned char* __restrict__ adjq,
                                             float* __restrict__ out) {
    __shared__ __attribute__((aligned(16))) float efsE[1024];   // 4 KB
    __shared__ __attribute__((aligned(16))) float efsF[1024];   // 4 KB
    __shared__ float m2s[4];

    const int tid   = threadIdx.x;
    const int b     = blockIdx.x & 7;
    const int t     = (blockIdx.x >> 3) & 7;
    const int itile = blockIdx.x >> 6;            // 0..7
    const int bt    = b * 8 + t;
    const int i0    = itile * 128;

    const int w   = tid >> 6;                     // wave 0..3 (row group)
    const int l   = tid & 63;
    const int col = l & 31;
    const int g   = l >> 5;                       // k-half group
    const int row = w * 32 + col;                 // block-local i-row

    const uint4* plane = Whf + (size_t)bt * 16384;
    const unsigned char* arow = adjq + ((size_t)(i0 + row) << 7) + (g << 6);

    // stage E/F + running max of h2; h1 direct per-thread
    const float* wh2g = Wh2 + bt * 1024;
    float mx = -1e30f;
    #pragma unroll
    for (int rep = 0; rep < 4; ++rep) {
        int   j  = tid + rep * 256;
        float h2 = wh2g[j];
        efsE[j] = __expf(h2);
        efsF[j] = __expf(ALPHA * h2);
        mx = fmaxf(mx, h2);
    }
    #pragma unroll
    for (int off = 1; off < 64; off <<= 1) mx = fmaxf(mx, __shfl_xor(mx, off));
    if (l == 0) m2s[w] = mx;
    const float h1 = Wh1[bt * 1024 + i0 + row];
    __syncthreads();                              // the ONLY barrier

    const float M2 = fmaxf(fmaxf(m2s[0], m2s[1]), fmaxf(m2s[2], m2s[3]));
    const float e0 = h1 + M2;
    const float mp = fmaxf(e0, ALPHA * e0);       // both products <= 1
    const float Af = __expf(h1 - mp);
    const float Bf = __expf(ALPHA * h1 - mp);

    f32x16 acc[4];
    #pragma unroll
    for (int nt2 = 0; nt2 < 4; ++nt2)
        #pragma unroll
        for (int r = 0; r < 16; ++r) acc[nt2][r] = 0.f;
    f32x16 accl;
    #pragma unroll
    for (int r = 0; r < 16; ++r) accl[r] = 0.f;

    bf16x8 ones;
    #pragma unroll
    for (int i = 0; i < 8; ++i) ones[i] = (short)0x3F80;

    union qb { uint4 u4; bf16x8 v8; };
    qb qX[4], qY[4];
    // prologue: qX <- frags(v=0, ts=0)
    #pragma unroll
    for (int nt2 = 0; nt2 < 4; ++nt2)
        qX[nt2].u4 = plane[(nt2 * 64 + 0) * 64 + l];

    #pragma unroll 1
    for (int v = 0; v < 16; ++v) {
        const uint32_t by32 = *(const uint32_t*)(arow + v * 4);
        TSBODY(0, qX, qY, v * 4 + 1)
        TSBODY(1, qY, qX, v * 4 + 2)
        TSBODY(2, qX, qY, v * 4 + 3)
        TSBODY(3, qY, qX, ((v + 1) & 15) * 4)
    }

    // epilogue: D rows r = (reg&3)+8*(reg>>2)+4*g; accl rows identical
    float* og = out + ((size_t)(b * 1024 + i0 + w * 32)) * 1024 + t;
    #pragma unroll
    for (int reg = 0; reg < 16; ++reg) {
        const int   r    = (reg & 3) + 8 * (reg >> 2) + 4 * g;
        const float linv = 1.0f / accl[reg];
        #pragma unroll
        for (int nt2 = 0; nt2 < 4; ++nt2) {
            float vv = acc[nt2][reg] * linv;
            vv = vv > 0.f ? vv : __expf(vv) - 1.f;
            og[(size_t)r * 1024 + (nt2 * 32 + col) * 8] = vv;
        }
    }
}

// ---------------------------------------------------------------------------
extern "C" void kernel_launch(void* const* d_in, const int* in_sizes, int n_in,
                              void* d_out, int out_size, void* d_ws, size_t ws_size,
                              hipStream_t stream) {
    const float* x   = (const float*)d_in[0];   // (8,1024,64,8)
    const float* adj = (const float*)d_in[1];   // (1024,1024)
    const float* W   = (const float*)d_in[2];   // (64,128)
    const float* a   = (const float*)d_in[3];   // (256,1)
    float* out = (float*)d_out;                 // (8,1024,128,8)

    uint4*         Whf  = (uint4*)d_ws;                        // 1048576 uint4 = 16 MB
    float*         Wh1  = (float*)(Whf + 1048576);             // 65536 f
    float*         Wh2  = Wh1 + 65536;                         // 65536 f
    unsigned char* adjq = (unsigned char*)(Wh2 + 65536);       // 131072 B

    k_pre<<<1024, 256, 0, stream>>>(x, W, a, adj, Whf, Wh1, Wh2, adjq);
    k_agg<<<512, 256, 0, stream>>>(Whf, Wh1, Wh2, adjq, out);
}